// Round 10
// baseline (680.669 us; speedup 1.0000x reference)
//
#include <hip/hip_runtime.h>
#include <math.h>

#define N_ROWS 16384
#define DIM    2048
#define K_CENT 1000
#define KPAD   1024
#define CDIM   2049   // D+1

// ---------------- MFMA-path workspace layout (bytes) ----------------
#define WS_AH   ((size_t)0)
#define WS_AL   ((size_t)67108864)
#define WS_BH   ((size_t)134217728)
#define WS_BL   ((size_t)138412032)
#define WS_RN   ((size_t)142606336)   // i2r = 0.5*||f||  (16384 f)
#define WS_CN2  ((size_t)142671872)
#define WS_CL   ((size_t)142675968)
#define WS_PV   ((size_t)142680064)   // 16384*8 f
#define WS_PI   ((size_t)143204352)   // 16384*8 i
#define WS_NEED ((size_t)143728640)

typedef __attribute__((ext_vector_type(8)))  short          bf16x8;  // MFMA A/B
typedef __attribute__((ext_vector_type(16))) float          f32x16;  // MFMA C/D 32x32
typedef __attribute__((ext_vector_type(8)))  unsigned short u16x8;   // 16B store

__device__ __forceinline__ unsigned short f2bf(float x){    // RNE fp32->bf16
  unsigned int u = __float_as_uint(x);
  u += 0x7fffu + ((u >> 16) & 1u);
  return (unsigned short)(u >> 16);
}
__device__ __forceinline__ float bf2f(unsigned short h){
  return __uint_as_float(((unsigned int)h) << 16);
}

typedef const __attribute__((address_space(1))) void gv_t;
typedef __attribute__((address_space(3))) void lv_t;
__device__ __forceinline__ void gload16(const void* g, void* l){
  __builtin_amdgcn_global_load_lds((gv_t*)g, (lv_t*)l, 16, 0, 0);
}

// ---------------- prep: feats -> (Ah,Al) bf16 split + i2r ------------------
// thread t owns 8 consecutive floats -> one 16B store per stream.
__global__ __launch_bounds__(256) void prep_feats(const float* __restrict__ feats,
    unsigned short* __restrict__ Ah, unsigned short* __restrict__ Al,
    float* __restrict__ i2r){
  const int row = blockIdx.x, t = threadIdx.x;
  const float4* p4 = (const float4*)(feats + (size_t)row * DIM);
  float4 u0 = p4[2*t], u1 = p4[2*t + 1];
  float e[8] = {u0.x,u0.y,u0.z,u0.w,u1.x,u1.y,u1.z,u1.w};
  float s = 0.f;
  u16x8 hv, lv;
  #pragma unroll
  for (int q = 0; q < 8; ++q){
    s = fmaf(e[q], e[q], s);
    unsigned short h = f2bf(e[q]);
    hv[q] = h; lv[q] = f2bf(e[q] - bf2f(h));
  }
  *(u16x8*)(Ah + (size_t)row*DIM + t*8) = hv;
  *(u16x8*)(Al + (size_t)row*DIM + t*8) = lv;
  #pragma unroll
  for (int mm = 1; mm < 64; mm <<= 1) s += __shfl_xor(s, mm, 64);
  __shared__ float wsm[4];
  if ((t & 63) == 0) wsm[t >> 6] = s;
  __syncthreads();
  if (t == 0){
    float tot = wsm[0]+wsm[1]+wsm[2]+wsm[3] + 1.0f;  // + appended-ones col
    i2r[row] = 0.5f * sqrtf(tot);                     // = 1/(2*rnorm)
  }
}

// ---------------- prep: centers -> (Bh,Bl) + cn2 + bias col ----------------
// coalesced scalar loads -> LDS row buffer -> 16B vector stores.
__global__ __launch_bounds__(256) void prep_cent(const float* __restrict__ initc,
    unsigned short* __restrict__ Bh, unsigned short* __restrict__ Bl,
    float* __restrict__ cn2, float* __restrict__ cl){
  const int j = blockIdx.x, t = threadIdx.x;
  __shared__ float rowbuf[DIM];
  __shared__ float wsm[4];
  if (j < K_CENT){
    const float* p = initc + (size_t)j * CDIM;
    float s = 0.f;
    #pragma unroll
    for (int i = 0; i < 8; ++i){
      float x = p[t + i*256];
      rowbuf[t + i*256] = x;
      s = fmaf(x, x, s);
    }
    #pragma unroll
    for (int mm = 1; mm < 64; mm <<= 1) s += __shfl_xor(s, mm, 64);
    if ((t & 63) == 0) wsm[t >> 6] = s;
    __syncthreads();
    if (t == 0){
      float xl = p[DIM];                 // bias column c[2048]
      cl[j] = xl;
      cn2[j] = wsm[0]+wsm[1]+wsm[2]+wsm[3] + xl*xl;
    }
    u16x8 hv, lv;
    #pragma unroll
    for (int q = 0; q < 8; ++q){
      float x = rowbuf[t*8 + q];
      unsigned short h = f2bf(x);
      hv[q] = h; lv[q] = f2bf(x - bf2f(h));
    }
    *(u16x8*)(Bh + (size_t)j*DIM + t*8) = hv;
    *(u16x8*)(Bl + (size_t)j*DIM + t*8) = lv;
  } else {                               // padded centers 1000..1023
    u16x8 z = (u16x8)0;
    *(u16x8*)(Bh + (size_t)j*DIM + t*8) = z;
    *(u16x8*)(Bl + (size_t)j*DIM + t*8) = z;
    if (t == 0){ cn2[j] = INFINITY; cl[j] = 0.f; }
  }
}

// ---------------- MFMA GEMM (bf16x3, 32x32x16) + fused argmin --------------
// Block 128x256, 4 waves 2x2; wave tile 64x128 = 2x4 frags of 32x32.
// Per K=32: 24 ds_read_b128 feed 48 MFMAs (reuse 4) -> MFMA-bound.
// LDS: Ah[kb4][row128][16B] @0, Al @8K, Bh[kb4][col256][16B] @16K, Bl @32K.
__global__ __launch_bounds__(256) void dist_mfma(
    const unsigned short* __restrict__ Ah, const unsigned short* __restrict__ Al,
    const unsigned short* __restrict__ Bh, const unsigned short* __restrict__ Bl,
    const float* __restrict__ i2r, const float* __restrict__ cn2,
    const float* __restrict__ cl, float* __restrict__ pval, int* __restrict__ pidx){
  __shared__ char smem[49152];
  const int t = threadIdx.x;
  const int l = t & 63, w = t >> 6;
  const int wr = w >> 1, wc = w & 1;
  const int rowBase = blockIdx.x * 128, colBase = blockIdx.y * 256;

  f32x16 acc[2][4];
  #pragma unroll
  for (int m = 0; m < 2; ++m)
    #pragma unroll
    for (int n = 0; n < 4; ++n)
      #pragma unroll
      for (int q = 0; q < 16; ++q) acc[m][n][q] = 0.f;

  // staging: A chunks c=t (kb=t>>7,row=t&127) and c=t+256 (kb+2, same row);
  //          B: thread t stages col t's 4 kb chunks.
  const int ar = t & 127, akb = t >> 7;
  const size_t gA0 = (size_t)(rowBase + ar)*DIM + akb*8;
  const size_t gA1 = gA0 + 16;                       // kb+2 -> +16 elems
  const size_t gBb = (size_t)(colBase + t)*DIM;
  const int ldA0 = t*16, ldA1 = (t+256)*16;

  for (int k0 = 0; k0 < DIM; k0 += 32){
    gload16(Ah + gA0 + k0, smem + ldA0);
    gload16(Ah + gA1 + k0, smem + ldA1);
    gload16(Al + gA0 + k0, smem + 8192  + ldA0);
    gload16(Al + gA1 + k0, smem + 8192  + ldA1);
    #pragma unroll
    for (int q = 0; q < 4; ++q){
      gload16(Bh + gBb + q*8 + k0, smem + 16384 + (q*256 + t)*16);
      gload16(Bl + gBb + q*8 + k0, smem + 32768 + (q*256 + t)*16);
    }
    __syncthreads();                     // drains vmcnt: tiles ready
    #pragma unroll
    for (int s = 0; s < 2; ++s){
      const int kb = s*2 + (l >> 5);
      bf16x8 ah[2], al[2];
      #pragma unroll
      for (int m = 0; m < 2; ++m){
        int arow = wr*64 + m*32 + (l & 31);
        ah[m] = *(const bf16x8*)(smem + (kb*128 + arow)*16);
        al[m] = *(const bf16x8*)(smem + 8192 + (kb*128 + arow)*16);
      }
      #pragma unroll
      for (int n = 0; n < 4; ++n){
        int boff = (kb*256 + wc*128 + n*32 + (l & 31))*16;
        bf16x8 bh = *(const bf16x8*)(smem + 16384 + boff);
        bf16x8 bl = *(const bf16x8*)(smem + 32768 + boff);
        #pragma unroll
        for (int m = 0; m < 2; ++m){
          acc[m][n] = __builtin_amdgcn_mfma_f32_32x32x16_bf16(ah[m], bh, acc[m][n], 0, 0, 0);
          acc[m][n] = __builtin_amdgcn_mfma_f32_32x32x16_bf16(ah[m], bl, acc[m][n], 0, 0, 0);
          acc[m][n] = __builtin_amdgcn_mfma_f32_32x32x16_bf16(al[m], bh, acc[m][n], 0, 0, 0);
        }
      }
    }
    __syncthreads();
  }

  // epilogue: 32x32 C/D map col=lane&31, row=(reg&3)+8*(reg>>2)+4*(lane>>5)
  // score v = cn2*i2r - dot - cl (monotone per row: original = 2rn*v, rn>0)
  float c2v[4], clv[4];
  #pragma unroll
  for (int n = 0; n < 4; ++n){
    int col = colBase + wc*128 + n*32 + (l & 31);
    c2v[n] = cn2[col]; clv[n] = cl[col];
  }
  #pragma unroll
  for (int m = 0; m < 2; ++m){
    #pragma unroll
    for (int reg = 0; reg < 16; ++reg){
      int row = rowBase + wr*64 + m*32 + (reg & 3) + 8*(reg >> 2) + 4*(l >> 5);
      float ir = i2r[row];
      float bestv = INFINITY; int besti = 0x7fffffff;
      #pragma unroll
      for (int n = 0; n < 4; ++n){
        float v = fmaf(c2v[n], ir, -(acc[m][n][reg] + clv[n]));  // padded: INF
        int ci = colBase + wc*128 + n*32 + (l & 31);
        if (v < bestv){ bestv = v; besti = ci; }
      }
      #pragma unroll
      for (int mm = 1; mm < 32; mm <<= 1){   // reduce 32 cols (stays in half)
        float ov = __shfl_xor(bestv, mm, 64);
        int   oi = __shfl_xor(besti, mm, 64);
        if (ov < bestv || (ov == bestv && oi < besti)){ bestv = ov; besti = oi; }
      }
      if ((l & 31) == 0){
        pval[row*8 + blockIdx.y*2 + wc] = bestv;
        pidx[row*8 + blockIdx.y*2 + wc] = besti;
      }
    }
  }
}

// ---------------- final argmin over NT tile partials -----------------------
template<int NT>
__global__ __launch_bounds__(256) void argmin_final(const float* __restrict__ pval,
    const int* __restrict__ pidx, const int* __restrict__ labels,
    int* __restrict__ out){
  const int i = blockIdx.x * 256 + threadIdx.x;
  float bestv = INFINITY; int besti = 0x7fffffff;
  #pragma unroll
  for (int s = 0; s < NT; ++s){
    float v = pval[i*NT + s]; int ix = pidx[i*NT + s];
    if (v < bestv || (v == bestv && ix < besti)){ bestv = v; besti = ix; }
  }
  out[i] = labels[besti];
}

// ==================== fp32 fallback path (verified round 8) ================
__global__ __launch_bounds__(256) void rnorm_kernel(const float* __restrict__ feats,
                                                    float* __restrict__ rnorm) {
    const int row = blockIdx.x;
    const int t = threadIdx.x;
    const float4* p4 = (const float4*)(feats + (size_t)row * DIM);
    float4 v0 = p4[t];
    float4 v1 = p4[t + 256];
    float s = v0.x*v0.x + v0.y*v0.y + v0.z*v0.z + v0.w*v0.w
            + v1.x*v1.x + v1.y*v1.y + v1.z*v1.z + v1.w*v1.w;
    #pragma unroll
    for (int m = 1; m < 64; m <<= 1) s += __shfl_xor(s, m, 64);
    __shared__ float ws[4];
    if ((t & 63) == 0) ws[t >> 6] = s;
    __syncthreads();
    if (t == 0) {
        float tot = ws[0] + ws[1] + ws[2] + ws[3] + 1.0f;
        rnorm[row] = 1.0f / sqrtf(tot);
    }
}

__global__ __launch_bounds__(256) void cn2_kernel(const float* __restrict__ initc,
                                                  float* __restrict__ cn2) {
    const int j = blockIdx.x;
    const int t = threadIdx.x;
    const float* p = initc + (size_t)j * CDIM;
    float s = 0.f;
    for (int i = t; i < CDIM; i += 256) { float v = p[i]; s = fmaf(v, v, s); }
    #pragma unroll
    for (int m = 1; m < 64; m <<= 1) s += __shfl_xor(s, m, 64);
    __shared__ float ws[4];
    if ((t & 63) == 0) ws[t >> 6] = s;
    __syncthreads();
    if (t == 0) cn2[j] = ws[0] + ws[1] + ws[2] + ws[3];
}

__global__ __launch_bounds__(256) void dist_kernel(const float* __restrict__ feats,
                                                   const float* __restrict__ initc,
                                                   const float* __restrict__ rnorm,
                                                   const float* __restrict__ cn2,
                                                   float* __restrict__ pval,
                                                   int* __restrict__ pidx) {
    __shared__ __align__(16) float As[16][128 + 4];
    __shared__ __align__(16) float Bs[16][128 + 4];
    const int bm = blockIdx.x;
    const int bn = blockIdx.y;
    const int t  = threadIdx.x;
    const int tx = t & 15;
    const int ty = t >> 4;
    const int rowBase  = bm * 128;
    const int centBase = bn * 128;
    float acc[8][8];
    #pragma unroll
    for (int i = 0; i < 8; ++i)
        #pragma unroll
        for (int j = 0; j < 8; ++j) acc[i][j] = 0.f;
    const int ar  = t >> 2;
    const int ac4 = (t & 3) << 2;
    const int bc  = t >> 4;
    const int bcol = t & 15;
    auto cidx = [&](int j) { return (j < 4) ? (tx * 4 + j) : (64 + tx * 4 + (j - 4)); };
    for (int k0 = 0; k0 < DIM; k0 += 16) {
        #pragma unroll
        for (int p = 0; p < 2; ++p) {
            int row = p * 64 + ar;
            const float4 v = *(const float4*)(feats + (size_t)(rowBase + row) * DIM + k0 + ac4);
            As[ac4 + 0][row] = v.x;
            As[ac4 + 1][row] = v.y;
            As[ac4 + 2][row] = v.z;
            As[ac4 + 3][row] = v.w;
        }
        #pragma unroll
        for (int p = 0; p < 8; ++p) {
            int cent = p * 16 + bc;
            int gj = centBase + cent;
            Bs[bcol][cent] = (gj < K_CENT) ? initc[(size_t)gj * CDIM + k0 + bcol] : 0.f;
        }
        __syncthreads();
        #pragma unroll
        for (int kk = 0; kk < 16; ++kk) {
            float a[8], b[8];
            *(float4*)&a[0] = *(const float4*)&As[kk][ty * 8];
            *(float4*)&a[4] = *(const float4*)&As[kk][ty * 8 + 4];
            *(float4*)&b[0] = *(const float4*)&Bs[kk][tx * 4];
            *(float4*)&b[4] = *(const float4*)&Bs[kk][64 + tx * 4];
            #pragma unroll
            for (int i = 0; i < 8; ++i)
                #pragma unroll
                for (int j = 0; j < 8; ++j)
                    acc[i][j] = fmaf(a[i], b[j], acc[i][j]);
        }
        __syncthreads();
    }
    float rn[8];
    #pragma unroll
    for (int i = 0; i < 8; ++i) rn[i] = rnorm[rowBase + ty * 8 + i];
    float cle[8], c2[8];
    #pragma unroll
    for (int j = 0; j < 8; ++j) {
        int gj = centBase + cidx(j);
        cle[j] = (gj < K_CENT) ? initc[(size_t)gj * CDIM + DIM] : 0.f;
        c2[j] = (gj < K_CENT) ? cn2[gj] : INFINITY;
    }
    #pragma unroll
    for (int i = 0; i < 8; ++i) {
        float bestv = INFINITY;
        int   besti = 0x7fffffff;
        #pragma unroll
        for (int j = 0; j < 8; ++j) {
            int gj = centBase + cidx(j);
            float v = (gj < K_CENT) ? (c2[j] - 2.0f * rn[i] * (acc[i][j] + cle[j])) : INFINITY;
            if (v < bestv) { bestv = v; besti = gj; }
        }
        #pragma unroll
        for (int m = 1; m < 16; m <<= 1) {
            float ov = __shfl_xor(bestv, m, 64);
            int   oi = __shfl_xor(besti, m, 64);
            if (ov < bestv || (ov == bestv && oi < besti)) { bestv = ov; besti = oi; }
        }
        if (tx == 0) {
            int row = rowBase + ty * 8 + i;
            pval[row * 8 + bn] = bestv;
            pidx[row * 8 + bn] = besti;
        }
    }
}

// ==================== launch ==============================================
extern "C" void kernel_launch(void* const* d_in, const int* in_sizes, int n_in,
                              void* d_out, int out_size, void* d_ws, size_t ws_size,
                              hipStream_t stream) {
    const float* feats  = (const float*)d_in[0];   // [16384, 2048] fp32
    const float* initc  = (const float*)d_in[1];   // [1000, 2049] fp32
    const int*   labels = (const int*)d_in[2];     // [1000] int32 (arange)
    int* out = (int*)d_out;                        // [16384] int32
    char* ws = (char*)d_ws;

    if (ws_size >= WS_NEED) {
        // -------- bf16x3 MFMA path (32x32x16) --------
        unsigned short* Ah = (unsigned short*)(ws + WS_AH);
        unsigned short* Al = (unsigned short*)(ws + WS_AL);
        unsigned short* Bh = (unsigned short*)(ws + WS_BH);
        unsigned short* Bl = (unsigned short*)(ws + WS_BL);
        float* ir  = (float*)(ws + WS_RN);
        float* c2  = (float*)(ws + WS_CN2);
        float* clp = (float*)(ws + WS_CL);
        float* pv  = (float*)(ws + WS_PV);
        int*   pi  = (int*)  (ws + WS_PI);

        prep_feats<<<N_ROWS, 256, 0, stream>>>(feats, Ah, Al, ir);
        prep_cent<<<KPAD, 256, 0, stream>>>(initc, Bh, Bl, c2, clp);
        dim3 grid(N_ROWS / 128, KPAD / 256);
        dist_mfma<<<grid, 256, 0, stream>>>(Ah, Al, Bh, Bl, ir, c2, clp, pv, pi);
        argmin_final<8><<<N_ROWS / 256, 256, 0, stream>>>(pv, pi, labels, out);
    } else {
        // -------- fp32 fallback (verified) --------
        float* rnorm = (float*)(ws);
        float* cn2   = (float*)(ws + 65536);
        float* pval  = (float*)(ws + 73728);
        int*   pidx  = (int*)  (ws + 73728 + 524288);

        rnorm_kernel<<<N_ROWS, 256, 0, stream>>>(feats, rnorm);
        cn2_kernel<<<K_CENT, 256, 0, stream>>>(initc, cn2);
        dim3 grid(N_ROWS / 128, 8);
        dist_kernel<<<grid, 256, 0, stream>>>(feats, initc, rnorm, cn2, pval, pidx);
        argmin_final<8><<<N_ROWS / 256, 256, 0, stream>>>(pval, pidx, labels, out);
    }
}